// Round 5
// baseline (453.071 us; speedup 1.0000x reference)
//
#include <hip/hip_runtime.h>
#include <stdint.h>

#define BB 4
#define LL 16384
#define CC 512
#define MM (BB * LL)  // 65536

typedef unsigned short u16;
typedef __bf16 bf16x8 __attribute__((ext_vector_type(8)));
typedef float f32x4 __attribute__((ext_vector_type(4)));
typedef u16 u16x8 __attribute__((ext_vector_type(8)));
typedef u16 u16x4 __attribute__((ext_vector_type(4)));

__device__ __forceinline__ u16 f2bf(float f) {
  return __builtin_bit_cast(u16, (__bf16)f);
}

__device__ __forceinline__ void gl_lds16(const void* g, void* l) {
  __builtin_amdgcn_global_load_lds((const __attribute__((address_space(1))) void*)g,
                                   (__attribute__((address_space(3))) void*)l,
                                   16, 0, 0);
}

// ---------------- fused fp32 -> bf16 convert for q and kv ----------------
__global__ void cvt2_kernel(const float* __restrict__ q, const float* __restrict__ kv,
                            u16* __restrict__ qo, u16* __restrict__ kvo, int n4) {
  for (int i = blockIdx.x * blockDim.x + threadIdx.x; i < 2 * n4; i += gridDim.x * blockDim.x) {
    const float* src = (i < n4) ? q : kv;
    u16* dst = (i < n4) ? qo : kvo;
    int k = (i < n4) ? i : i - n4;
    float4 v = reinterpret_cast<const float4*>(src)[k];
    u16x4 o;
    o[0] = f2bf(v.x); o[1] = f2bf(v.y); o[2] = f2bf(v.z); o[3] = f2bf(v.w);
    reinterpret_cast<u16x4*>(dst)[k] = o;
  }
}

// ------------- fused weight transpose+convert: W[K][N] -> Wt[N][K] bf16 -------------
__global__ void tcvt3_kernel(const float* __restrict__ Wq, const float* __restrict__ Wkv,
                             const float* __restrict__ Wfc, u16* __restrict__ Wq_t,
                             u16* __restrict__ Wkv_t, u16* __restrict__ Wfc_t) {
  int idx = blockIdx.x * blockDim.x + threadIdx.x;  // 0 .. 1048575
  const float* W; u16* Wt; int N, li;
  if (idx < 262144)      { W = Wq;  Wt = Wq_t;  N = 512;  li = idx; }
  else if (idx < 786432) { W = Wkv; Wt = Wkv_t; N = 1024; li = idx - 262144; }
  else                   { W = Wfc; Wt = Wfc_t; N = 512;  li = idx - 786432; }
  int n = li / 512, k = li % 512;
  Wt[li] = f2bf(W[k * N + n]);
}

// ---------------- 256x256 8-phase NT GEMM: C[M][N] = A[M][K] * Bt[N][K]^T ----------
// BM=BN=256, BK=64, 8 waves (2M x 4N), double-buffered LDS, T2 XOR-swizzle,
// counted vmcnt, setprio around MFMA clusters. K must be a multiple of 128.
// Stage discipline: a gl_lds may only target a region whose last reads are
// closed by an end-of-phase barrier. A reads span all 4 phases -> A(u+1) is
// staged into the opposite-parity (idle) buffer @p1/p2. B reads are all in
// phase 1 -> B(u+2) staged into same-parity buffer @p3/p4. vmcnt(4) per tile.
template <bool OUT_F32>
__global__ __launch_bounds__(512, 2) void gemm256(const u16* __restrict__ A,
                                                  const u16* __restrict__ Bt,
                                                  void* __restrict__ Cp,
                                                  int M, int N, int K) {
  __shared__ __align__(16) u16 Al[2][16384];
  __shared__ __align__(16) u16 Bl[2][16384];
  const int nbn = N >> 8;
  const int nwg = gridDim.x;
  const int bid0 = blockIdx.x;
  const int cpx = nwg >> 3;  // grid % 8 == 0 for all our shapes
  const int bid = (bid0 & 7) * cpx + (bid0 >> 3);
  const int bm = bid / nbn, bn = bid % nbn;
  const size_t row0 = (size_t)bm << 8, col0 = (size_t)bn << 8;
  const int tid = threadIdx.x, lane = tid & 63;
  const int wv = tid >> 6, wm = wv >> 2, wn = wv & 3;
  const int ro = lane & 15, g4 = lane >> 4;
  const int NT = K >> 6;

  // staging geometry: chunk ci covers (row=ci>>3, colgroup=ci&7) of a 128x64 half-tile.
  // LDS dest is LINEAR; global source colgroup pre-swizzled: gg = g ^ (row&7).
  const int ci0 = tid, ci1 = tid + 512;
  const int r0 = ci0 >> 3, g0 = (ci0 & 7) ^ (r0 & 7);
  const int r1 = ci1 >> 3, g1 = (ci1 & 7) ^ (r1 & 7);

  auto stageA = [&](int half, int kt, u16* L) {
    gl_lds16(A + (row0 + half * 128 + r0) * (size_t)K + kt * 64 + g0 * 8, L + half * 8192 + ci0 * 8);
    gl_lds16(A + (row0 + half * 128 + r1) * (size_t)K + kt * 64 + g1 * 8, L + half * 8192 + ci1 * 8);
  };
  auto stageB = [&](int half, int kt, u16* L) {
    gl_lds16(Bt + (col0 + half * 128 + r0) * (size_t)K + kt * 64 + g0 * 8, L + half * 8192 + ci0 * 8);
    gl_lds16(Bt + (col0 + half * 128 + r1) * (size_t)K + kt * 64 + g1 * 8, L + half * 8192 + ci1 * 8);
  };

  // ds_read offsets (u16 elements), swizzled: phys colgroup = logical ^ (row&7)
  const int aB = (wm * 128 + ro) * 64;
  const int bB = (wn * 64 + ro) * 64;
  const int sw0 = (g4 ^ (ro & 7)) * 8;
  const int sw1 = ((g4 + 4) ^ (ro & 7)) * 8;

  auto ldf = [&](const u16* p) { return *reinterpret_cast<const bf16x8*>(p); };

  f32x4 acc[8][4] = {};

  // prologue: tile 0 fully + B of tile 1. Queue: [A(0)^4, B(0)^4, B(1)^4].
  stageA(0, 0, Al[0]); stageA(1, 0, Al[0]); stageB(0, 0, Bl[0]); stageB(1, 0, Bl[0]);
  stageB(0, 1, Bl[1]); stageB(1, 1, Bl[1]);
  asm volatile("s_waitcnt vmcnt(4)" ::: "memory");  // drain A(0)+B(0); B(1) in flight
  __builtin_amdgcn_s_barrier();

  for (int t = 0; t < NT; t += 2) {
#pragma unroll
    for (int half = 0; half < 2; ++half) {
      const int u = t + half;
      u16* LA = Al[half];
      u16* LB = Bl[half];
      u16* LAn = Al[half ^ 1];
      const bool stA = (u + 1) < NT;
      const bool stB = (u + 2) < NT;
      bf16x8 bfr[4][2], af[2][2];

      // ---- phase 1: all B frags + A m0,m1; stage A half0 (u+1) into idle buffer ----
#pragma unroll
      for (int n = 0; n < 4; ++n) {
        bfr[n][0] = ldf(LB + bB + n * 1024 + sw0);
        bfr[n][1] = ldf(LB + bB + n * 1024 + sw1);
      }
      af[0][0] = ldf(LA + aB + sw0);        af[0][1] = ldf(LA + aB + sw1);
      af[1][0] = ldf(LA + aB + 1024 + sw0); af[1][1] = ldf(LA + aB + 1024 + sw1);
      if (stA) stageA(0, u + 1, LAn);
      __builtin_amdgcn_s_barrier();
      asm volatile("s_waitcnt lgkmcnt(0)" ::: "memory");
      __builtin_amdgcn_sched_barrier(0);
      __builtin_amdgcn_s_setprio(1);
#pragma unroll
      for (int m = 0; m < 2; ++m)
#pragma unroll
        for (int n = 0; n < 4; ++n) {
          acc[m][n] = __builtin_amdgcn_mfma_f32_16x16x32_bf16(af[m][0], bfr[n][0], acc[m][n], 0, 0, 0);
          acc[m][n] = __builtin_amdgcn_mfma_f32_16x16x32_bf16(af[m][1], bfr[n][1], acc[m][n], 0, 0, 0);
        }
      __builtin_amdgcn_s_setprio(0);
      __builtin_amdgcn_s_barrier();

      // ---- phases 2..4: A m=2ph..2ph+1; stage Ah1(u+1) / Bh0(u+2) / Bh1(u+2) ----
#pragma unroll
      for (int ph = 1; ph < 4; ++ph) {
        af[0][0] = ldf(LA + aB + (2 * ph) * 1024 + sw0);
        af[0][1] = ldf(LA + aB + (2 * ph) * 1024 + sw1);
        af[1][0] = ldf(LA + aB + (2 * ph + 1) * 1024 + sw0);
        af[1][1] = ldf(LA + aB + (2 * ph + 1) * 1024 + sw1);
        if (ph == 1) { if (stA) stageA(1, u + 1, LAn); }
        else if (ph == 2) { if (stB) stageB(0, u + 2, LB); }
        else { if (stB) stageB(1, u + 2, LB); }
        __builtin_amdgcn_s_barrier();
        asm volatile("s_waitcnt lgkmcnt(0)" ::: "memory");
        __builtin_amdgcn_sched_barrier(0);
        __builtin_amdgcn_s_setprio(1);
#pragma unroll
        for (int m = 0; m < 2; ++m)
#pragma unroll
          for (int n = 0; n < 4; ++n) {
            acc[2 * ph + m][n] =
                __builtin_amdgcn_mfma_f32_16x16x32_bf16(af[m][0], bfr[n][0], acc[2 * ph + m][n], 0, 0, 0);
            acc[2 * ph + m][n] =
                __builtin_amdgcn_mfma_f32_16x16x32_bf16(af[m][1], bfr[n][1], acc[2 * ph + m][n], 0, 0, 0);
          }
        __builtin_amdgcn_s_setprio(0);
        if (ph == 3) {
          if (stB) asm volatile("s_waitcnt vmcnt(4)" ::: "memory");
          else     asm volatile("s_waitcnt vmcnt(0)" ::: "memory");
        }
        __builtin_amdgcn_s_barrier();
      }
    }
  }

  // epilogue: C write
#pragma unroll
  for (int m = 0; m < 8; ++m)
#pragma unroll
    for (int n = 0; n < 4; ++n)
#pragma unroll
      for (int j = 0; j < 4; ++j) {
        size_t r = row0 + wm * 128 + m * 16 + g4 * 4 + j;
        size_t c = col0 + wn * 64 + n * 16 + ro;
        if (OUT_F32)
          reinterpret_cast<float*>(Cp)[r * N + c] = acc[m][n][j];
        else
          reinterpret_cast<u16*>(Cp)[r * N + c] = f2bf(acc[m][n][j]);
      }
}

// ---------------- window attention ----------------
// grid: b*512 + w*8 + h  (2048 blocks), 512 threads (8 waves, 32 q-rows each).
// K frags read directly from global (L1/L2-resident 32KB tile). V transposed in
// LDS; P staged per-wave in LDS half the keys at a time (split-ks). LDS 68.6KB
// -> 2 blocks/CU.
__global__ __launch_bounds__(512, 4) void attn_kernel(const u16* __restrict__ qp,
                                                      const u16* __restrict__ kvp,
                                                      u16* __restrict__ o) {
  __shared__ __align__(16) u16 Vt[64 * 264];        // V transposed, padded rows
  __shared__ __align__(16) u16 Pl[8][16 * 136];     // per-wave P row-tile (half keys)
  const int bid = blockIdx.x;
  const int h = bid & 7, w = (bid >> 3) & 63, b = bid >> 9;
  const int w1 = w >> 3, w2 = w & 7;
  const int tid = threadIdx.x, lane = tid & 63, wv = tid >> 6;

  auto lrow = [&](int t) { return (w1 * 16 + (t >> 4)) * 128 + w2 * 16 + (t & 15); };

  {  // stage V transposed
    const int t = tid >> 1, half = tid & 1;
    const size_t base = ((size_t)(b * LL + lrow(t))) * 1024 + h * 64 + half * 32;
    const u16* vr = kvp + base + 512;
#pragma unroll
    for (int c = 0; c < 4; ++c) {
      u16x8 vx = *reinterpret_cast<const u16x8*>(vr + c * 8);
#pragma unroll
      for (int e = 0; e < 8; ++e) Vt[(half * 32 + c * 8 + e) * 264 + t] = vx[e];
    }
  }
  __syncthreads();

  const int ro = lane & 15;       // low nibble
  const int g4 = lane >> 4;       // lane group 0..3
  const float scale = 0.125f;     // hd^-0.5, hd=64
  u16* PW = &Pl[wv][0];

  // per-lane K base: token = lrow(16*ct + ro) = w1*2048 + ct*128 + w2*16 + ro
  const u16* kp = kvp + ((size_t)(b * LL) + w1 * 2048 + w2 * 16 + ro) * 1024 + h * 64 + g4 * 8;

#pragma unroll
  for (int rt = 0; rt < 2; ++rt) {
    // Q fragments for this 16-row tile, direct from global
    const int tq = 32 * wv + 16 * rt + ro;
    const size_t qbase = ((size_t)(b * LL + lrow(tq))) * 512 + h * 64 + g4 * 8;
    const bf16x8 qf0 = *reinterpret_cast<const bf16x8*>(qp + qbase);
    const bf16x8 qf1 = *reinterpret_cast<const bf16x8*>(qp + qbase + 32);

    // S = Q K^T : 16 q-rows x 256 keys; K frags from global (row-major kvp)
    f32x4 sa[16] = {};
#pragma unroll
    for (int ct = 0; ct < 16; ++ct) {
      bf16x8 kf0 = *reinterpret_cast<const bf16x8*>(kp + ct * 131072);
      bf16x8 kf1 = *reinterpret_cast<const bf16x8*>(kp + ct * 131072 + 32);
      sa[ct] = __builtin_amdgcn_mfma_f32_16x16x32_bf16(qf0, kf0, sa[ct], 0, 0, 0);
      sa[ct] = __builtin_amdgcn_mfma_f32_16x16x32_bf16(qf1, kf1, sa[ct], 0, 0, 0);
    }

    // softmax per q-row (row = g4*4 + j, key = 16*ct + ro)
#pragma unroll
    for (int j = 0; j < 4; ++j) {
      float m = -1e30f;
#pragma unroll
      for (int ct = 0; ct < 16; ++ct) m = fmaxf(m, sa[ct][j]);
      m = fmaxf(m, __shfl_xor(m, 1));
      m = fmaxf(m, __shfl_xor(m, 2));
      m = fmaxf(m, __shfl_xor(m, 4));
      m = fmaxf(m, __shfl_xor(m, 8));
      m *= scale;
      float s = 0.f;
#pragma unroll
      for (int ct = 0; ct < 16; ++ct) {
        float p = __expf(sa[ct][j] * scale - m);
        sa[ct][j] = p;
        s += p;
      }
      s += __shfl_xor(s, 1);
      s += __shfl_xor(s, 2);
      s += __shfl_xor(s, 4);
      s += __shfl_xor(s, 8);
      float inv = 1.f / s;
#pragma unroll
      for (int ct = 0; ct < 16; ++ct) sa[ct][j] *= inv;
    }

    // O = P V in two key-halves through the per-wave LDS P tile.
    // In-wave DS ordering makes write->read->overwrite safe without barriers.
    f32x4 oacc[4] = {};
#pragma unroll
    for (int kh = 0; kh < 2; ++kh) {
#pragma unroll
      for (int j = 0; j < 4; ++j)
#pragma unroll
        for (int c = 0; c < 8; ++c)
          PW[(g4 * 4 + j) * 136 + 16 * c + ro] = f2bf(sa[kh * 8 + c][j]);
#pragma unroll
      for (int ks = 0; ks < 4; ++ks) {
        bf16x8 pf = *reinterpret_cast<const bf16x8*>(&PW[ro * 136 + ks * 32 + g4 * 8]);
#pragma unroll
        for (int cd = 0; cd < 4; ++cd) {
          bf16x8 vf = *reinterpret_cast<const bf16x8*>(
              &Vt[(16 * cd + ro) * 264 + (kh * 4 + ks) * 32 + g4 * 8]);
          oacc[cd] = __builtin_amdgcn_mfma_f32_16x16x32_bf16(pf, vf, oacc[cd], 0, 0, 0);
        }
      }
    }

    // write out this 16-row tile
#pragma unroll
    for (int cd = 0; cd < 4; ++cd)
#pragma unroll
      for (int j = 0; j < 4; ++j) {
        int t = 32 * wv + 16 * rt + g4 * 4 + j;
        int d = 16 * cd + ro;
        o[((size_t)(b * LL + lrow(t))) * 512 + h * 64 + d] = f2bf(oacc[cd][j]);
      }
  }
}

// ---------------- launch ----------------
extern "C" void kernel_launch(void* const* d_in, const int* in_sizes, int n_in,
                              void* d_out, int out_size, void* d_ws, size_t ws_size,
                              hipStream_t stream) {
  const float* q = (const float*)d_in[0];
  const float* kv = (const float*)d_in[1];
  const float* Wq = (const float*)d_in[2];
  const float* Wkv = (const float*)d_in[3];
  const float* Wfc = (const float*)d_in[4];
  float* out = (float*)d_out;
  char* ws = (char*)d_ws;

  // workspace layout (bytes)
  u16* q_bf  = (u16*)(ws + 0);            // 67108864  (also reused as o_buf)
  u16* kv_bf = (u16*)(ws + 67108864);     // 67108864
  u16* qp    = (u16*)(ws + 134217728);    // 67108864
  u16* kvp   = (u16*)(ws + 201326592);    // 134217728
  u16* Wq_t  = (u16*)(ws + 335544320);    // 524288
  u16* Wkv_t = (u16*)(ws + 336068608);    // 1048576
  u16* Wfc_t = (u16*)(ws + 337117184);    // 524288
  u16* o_buf = q_bf;                      // q_bf dead after GEMM1

  const int n4 = MM * CC / 4;  // 8388608
  cvt2_kernel<<<4096, 256, 0, stream>>>(q, kv, q_bf, kv_bf, n4);
  tcvt3_kernel<<<4096, 256, 0, stream>>>(Wq, Wkv, Wfc, Wq_t, Wkv_t, Wfc_t);

  gemm256<false><<<(MM / 256) * (CC / 256), 512, 0, stream>>>(q_bf, Wq_t, qp, MM, CC, CC);
  gemm256<false><<<(MM / 256) * (2 * CC / 256), 512, 0, stream>>>(kv_bf, Wkv_t, kvp, MM, 2 * CC, CC);

  attn_kernel<<<BB * 64 * 8, 512, 0, stream>>>(qp, kvp, o_buf);

  gemm256<true><<<(MM / 256) * (CC / 256), 512, 0, stream>>>(o_buf, Wfc_t, out, MM, CC, CC);
}

// Round 6
// 370.971 us; speedup vs baseline: 1.2213x; 1.2213x over previous
//
#include <hip/hip_runtime.h>
#include <stdint.h>

#define BB 4
#define LL 16384
#define CC 512
#define MM (BB * LL)  // 65536

typedef unsigned short u16;
typedef __bf16 bf16x8 __attribute__((ext_vector_type(8)));
typedef float f32x4 __attribute__((ext_vector_type(4)));
typedef u16 u16x8 __attribute__((ext_vector_type(8)));
typedef u16 u16x4 __attribute__((ext_vector_type(4)));

__device__ __forceinline__ u16 f2bf(float f) {
  return __builtin_bit_cast(u16, (__bf16)f);
}

__device__ __forceinline__ void gl_lds16(const void* g, void* l) {
  __builtin_amdgcn_global_load_lds((const __attribute__((address_space(1))) void*)g,
                                   (__attribute__((address_space(3))) void*)l,
                                   16, 0, 0);
}

// ---------------- fused fp32 -> bf16 convert for q and kv ----------------
__global__ void cvt2_kernel(const float* __restrict__ q, const float* __restrict__ kv,
                            u16* __restrict__ qo, u16* __restrict__ kvo, int n4) {
  for (int i = blockIdx.x * blockDim.x + threadIdx.x; i < 2 * n4; i += gridDim.x * blockDim.x) {
    const float* src = (i < n4) ? q : kv;
    u16* dst = (i < n4) ? qo : kvo;
    int k = (i < n4) ? i : i - n4;
    float4 v = reinterpret_cast<const float4*>(src)[k];
    u16x4 o;
    o[0] = f2bf(v.x); o[1] = f2bf(v.y); o[2] = f2bf(v.z); o[3] = f2bf(v.w);
    reinterpret_cast<u16x4*>(dst)[k] = o;
  }
}

// ------------- fused weight transpose+convert: W[K][N] -> Wt[N][K] bf16 -------------
__global__ void tcvt3_kernel(const float* __restrict__ Wq, const float* __restrict__ Wkv,
                             const float* __restrict__ Wfc, u16* __restrict__ Wq_t,
                             u16* __restrict__ Wkv_t, u16* __restrict__ Wfc_t) {
  int idx = blockIdx.x * blockDim.x + threadIdx.x;  // 0 .. 1048575
  const float* W; u16* Wt; int N, li;
  if (idx < 262144)      { W = Wq;  Wt = Wq_t;  N = 512;  li = idx; }
  else if (idx < 786432) { W = Wkv; Wt = Wkv_t; N = 1024; li = idx - 262144; }
  else                   { W = Wfc; Wt = Wfc_t; N = 512;  li = idx - 786432; }
  int n = li / 512, k = li % 512;
  Wt[li] = f2bf(W[k * N + n]);
}

// ---------------- 256x256 8-phase NT GEMM: C[M][N] = A[M][K] * Bt[N][K]^T ----------
// BM=BN=256, BK=64, 8 waves (2M x 4N), double-buffered LDS, T2 XOR-swizzle,
// counted vmcnt, setprio around MFMA clusters. K must be a multiple of 128.
// Stage discipline: a gl_lds may only target a region whose last reads are
// closed by an end-of-phase barrier. A reads span all 4 phases -> A(u+1) is
// staged into the opposite-parity (idle) buffer @p1/p2. B reads are all in
// phase 1 -> B(u+2) staged into same-parity buffer @p3/p4. vmcnt(4) per tile.
template <bool OUT_F32>
__global__ __launch_bounds__(512, 2) void gemm256(const u16* __restrict__ A,
                                                  const u16* __restrict__ Bt,
                                                  void* __restrict__ Cp,
                                                  int M, int N, int K) {
  __shared__ __align__(16) u16 Al[2][16384];
  __shared__ __align__(16) u16 Bl[2][16384];
  const int nbn = N >> 8;
  const int nwg = gridDim.x;
  const int bid0 = blockIdx.x;
  const int cpx = nwg >> 3;  // grid % 8 == 0 for all our shapes
  const int bid = (bid0 & 7) * cpx + (bid0 >> 3);
  const int bm = bid / nbn, bn = bid % nbn;
  const size_t row0 = (size_t)bm << 8, col0 = (size_t)bn << 8;
  const int tid = threadIdx.x, lane = tid & 63;
  const int wv = tid >> 6, wm = wv >> 2, wn = wv & 3;
  const int ro = lane & 15, g4 = lane >> 4;
  const int NT = K >> 6;

  // staging geometry: chunk ci covers (row=ci>>3, colgroup=ci&7) of a 128x64 half-tile.
  // LDS dest is LINEAR; global source colgroup pre-swizzled: gg = g ^ (row&7).
  const int ci0 = tid, ci1 = tid + 512;
  const int r0 = ci0 >> 3, g0 = (ci0 & 7) ^ (r0 & 7);
  const int r1 = ci1 >> 3, g1 = (ci1 & 7) ^ (r1 & 7);

  auto stageA = [&](int half, int kt, u16* L) {
    gl_lds16(A + (row0 + half * 128 + r0) * (size_t)K + kt * 64 + g0 * 8, L + half * 8192 + ci0 * 8);
    gl_lds16(A + (row0 + half * 128 + r1) * (size_t)K + kt * 64 + g1 * 8, L + half * 8192 + ci1 * 8);
  };
  auto stageB = [&](int half, int kt, u16* L) {
    gl_lds16(Bt + (col0 + half * 128 + r0) * (size_t)K + kt * 64 + g0 * 8, L + half * 8192 + ci0 * 8);
    gl_lds16(Bt + (col0 + half * 128 + r1) * (size_t)K + kt * 64 + g1 * 8, L + half * 8192 + ci1 * 8);
  };

  // ds_read offsets (u16 elements), swizzled: phys colgroup = logical ^ (row&7)
  const int aB = (wm * 128 + ro) * 64;
  const int bB = (wn * 64 + ro) * 64;
  const int sw0 = (g4 ^ (ro & 7)) * 8;
  const int sw1 = ((g4 + 4) ^ (ro & 7)) * 8;

  auto ldf = [&](const u16* p) { return *reinterpret_cast<const bf16x8*>(p); };

  f32x4 acc[8][4] = {};

  // prologue: tile 0 fully + B of tile 1. Queue: [A(0)^4, B(0)^4, B(1)^4].
  stageA(0, 0, Al[0]); stageA(1, 0, Al[0]); stageB(0, 0, Bl[0]); stageB(1, 0, Bl[0]);
  stageB(0, 1, Bl[1]); stageB(1, 1, Bl[1]);
  asm volatile("s_waitcnt vmcnt(4)" ::: "memory");  // drain A(0)+B(0); B(1) in flight
  __builtin_amdgcn_s_barrier();

  for (int t = 0; t < NT; t += 2) {
#pragma unroll
    for (int half = 0; half < 2; ++half) {
      const int u = t + half;
      u16* LA = Al[half];
      u16* LB = Bl[half];
      u16* LAn = Al[half ^ 1];
      const bool stA = (u + 1) < NT;
      const bool stB = (u + 2) < NT;
      bf16x8 bfr[4][2], af[2][2];

      // ---- phase 1: all B frags + A m0,m1; stage A half0 (u+1) into idle buffer ----
#pragma unroll
      for (int n = 0; n < 4; ++n) {
        bfr[n][0] = ldf(LB + bB + n * 1024 + sw0);
        bfr[n][1] = ldf(LB + bB + n * 1024 + sw1);
      }
      af[0][0] = ldf(LA + aB + sw0);        af[0][1] = ldf(LA + aB + sw1);
      af[1][0] = ldf(LA + aB + 1024 + sw0); af[1][1] = ldf(LA + aB + 1024 + sw1);
      if (stA) stageA(0, u + 1, LAn);
      __builtin_amdgcn_s_barrier();
      asm volatile("s_waitcnt lgkmcnt(0)" ::: "memory");
      __builtin_amdgcn_sched_barrier(0);
      __builtin_amdgcn_s_setprio(1);
#pragma unroll
      for (int m = 0; m < 2; ++m)
#pragma unroll
        for (int n = 0; n < 4; ++n) {
          acc[m][n] = __builtin_amdgcn_mfma_f32_16x16x32_bf16(af[m][0], bfr[n][0], acc[m][n], 0, 0, 0);
          acc[m][n] = __builtin_amdgcn_mfma_f32_16x16x32_bf16(af[m][1], bfr[n][1], acc[m][n], 0, 0, 0);
        }
      __builtin_amdgcn_s_setprio(0);
      __builtin_amdgcn_s_barrier();

      // ---- phases 2..4: A m=2ph..2ph+1; stage Ah1(u+1) / Bh0(u+2) / Bh1(u+2) ----
#pragma unroll
      for (int ph = 1; ph < 4; ++ph) {
        af[0][0] = ldf(LA + aB + (2 * ph) * 1024 + sw0);
        af[0][1] = ldf(LA + aB + (2 * ph) * 1024 + sw1);
        af[1][0] = ldf(LA + aB + (2 * ph + 1) * 1024 + sw0);
        af[1][1] = ldf(LA + aB + (2 * ph + 1) * 1024 + sw1);
        if (ph == 1) { if (stA) stageA(1, u + 1, LAn); }
        else if (ph == 2) { if (stB) stageB(0, u + 2, LB); }
        else { if (stB) stageB(1, u + 2, LB); }
        __builtin_amdgcn_s_barrier();
        asm volatile("s_waitcnt lgkmcnt(0)" ::: "memory");
        __builtin_amdgcn_sched_barrier(0);
        __builtin_amdgcn_s_setprio(1);
#pragma unroll
        for (int m = 0; m < 2; ++m)
#pragma unroll
          for (int n = 0; n < 4; ++n) {
            acc[2 * ph + m][n] =
                __builtin_amdgcn_mfma_f32_16x16x32_bf16(af[m][0], bfr[n][0], acc[2 * ph + m][n], 0, 0, 0);
            acc[2 * ph + m][n] =
                __builtin_amdgcn_mfma_f32_16x16x32_bf16(af[m][1], bfr[n][1], acc[2 * ph + m][n], 0, 0, 0);
          }
        __builtin_amdgcn_s_setprio(0);
        if (ph == 3) {
          if (stB) asm volatile("s_waitcnt vmcnt(4)" ::: "memory");
          else     asm volatile("s_waitcnt vmcnt(0)" ::: "memory");
        }
        __builtin_amdgcn_s_barrier();
      }
    }
  }

  // epilogue: C write
#pragma unroll
  for (int m = 0; m < 8; ++m)
#pragma unroll
    for (int n = 0; n < 4; ++n)
#pragma unroll
      for (int j = 0; j < 4; ++j) {
        size_t r = row0 + wm * 128 + m * 16 + g4 * 4 + j;
        size_t c = col0 + wn * 64 + n * 16 + ro;
        if (OUT_F32)
          reinterpret_cast<float*>(Cp)[r * N + c] = acc[m][n][j];
        else
          reinterpret_cast<u16*>(Cp)[r * N + c] = f2bf(acc[m][n][j]);
      }
}

// ---------------- window attention ----------------
// grid: b*512 + w*8 + h  (2048 blocks), 512 threads (8 waves, 32 q-rows each).
// K in LDS via global_load_lds with pre-swizzled source (32KB); V transposed in
// LDS, XOR-swizzled (32KB); P per-wave quarter-split, XOR-swizzled (16KB).
// Total exactly 80KB -> 2 blocks/CU.
__global__ __launch_bounds__(512, 4) void attn_kernel(const u16* __restrict__ qp,
                                                      const u16* __restrict__ kvp,
                                                      u16* __restrict__ o) {
  __shared__ __align__(16) u16 Kl[256 * 64];
  __shared__ __align__(16) u16 Vt[64 * 256];
  __shared__ __align__(16) u16 Pl[8 * 1024];
  const int bid = blockIdx.x;
  const int h = bid & 7, w = (bid >> 3) & 63, b = bid >> 9;
  const int w1 = w >> 3, w2 = w & 7;
  const int tid = threadIdx.x, lane = tid & 63, wv = tid >> 6;

  auto lrow = [&](int t) { return (w1 * 16 + (t >> 4)) * 128 + w2 * 16 + (t & 15); };

  // stage K: 2048 16B chunks; chunk ci = (row r = ci>>3, colgroup g = ci&7).
  // LDS dest linear; global source colgroup pre-swizzled g^(r&7).
#pragma unroll
  for (int p = 0; p < 4; ++p) {
    int ci = tid + p * 512;
    int r = ci >> 3, g = (ci & 7) ^ (r & 7);
    gl_lds16(kvp + ((size_t)(b * LL + lrow(r))) * 1024 + h * 64 + g * 8, Kl + ci * 8);
  }
  // stage V transposed, swizzled: logical (d, tk) at phys d*256 + ((tk>>3)^(d&7))*8 + (tk&7)
  {
    const int tk = tid >> 1, half = tid & 1;
    const size_t base = ((size_t)(b * LL + lrow(tk))) * 1024 + 512 + h * 64 + half * 32;
#pragma unroll
    for (int c = 0; c < 4; ++c) {
      u16x8 vx = *reinterpret_cast<const u16x8*>(kvp + base + c * 8);
#pragma unroll
      for (int e = 0; e < 8; ++e) {
        int d = half * 32 + c * 8 + e;
        Vt[d * 256 + (((tk >> 3) ^ (d & 7)) * 8) + (tk & 7)] = vx[e];
      }
    }
  }
  __syncthreads();

  const int ro = lane & 15;       // low nibble
  const int g4 = lane >> 4;       // lane group 0..3
  const float scale = 0.125f;     // hd^-0.5, hd=64
  const int swA = (g4 ^ (ro & 7)) * 8;
  const int swB = ((g4 + 4) ^ (ro & 7)) * 8;
  u16* PW = Pl + wv * 1024;

  auto ldf = [&](const u16* p) { return *reinterpret_cast<const bf16x8*>(p); };

#pragma unroll
  for (int rt = 0; rt < 2; ++rt) {
    // Q fragments for this 16-row tile, direct from global
    const int tq = 32 * wv + 16 * rt + ro;
    const size_t qbase = ((size_t)(b * LL + lrow(tq))) * 512 + h * 64 + g4 * 8;
    const bf16x8 qf0 = *reinterpret_cast<const bf16x8*>(qp + qbase);
    const bf16x8 qf1 = *reinterpret_cast<const bf16x8*>(qp + qbase + 32);

    // S = Q K^T : 16 q-rows x 256 keys; K frags from swizzled LDS
    f32x4 sa[16] = {};
    __builtin_amdgcn_s_setprio(1);
#pragma unroll
    for (int ct = 0; ct < 16; ++ct) {
      bf16x8 kf0 = ldf(Kl + (16 * ct + ro) * 64 + swA);
      bf16x8 kf1 = ldf(Kl + (16 * ct + ro) * 64 + swB);
      sa[ct] = __builtin_amdgcn_mfma_f32_16x16x32_bf16(qf0, kf0, sa[ct], 0, 0, 0);
      sa[ct] = __builtin_amdgcn_mfma_f32_16x16x32_bf16(qf1, kf1, sa[ct], 0, 0, 0);
    }
    __builtin_amdgcn_s_setprio(0);

    // softmax per q-row (row = g4*4 + j, key = 16*ct + ro)
#pragma unroll
    for (int j = 0; j < 4; ++j) {
      float m = -1e30f;
#pragma unroll
      for (int ct = 0; ct < 16; ++ct) m = fmaxf(m, sa[ct][j]);
      m = fmaxf(m, __shfl_xor(m, 1));
      m = fmaxf(m, __shfl_xor(m, 2));
      m = fmaxf(m, __shfl_xor(m, 4));
      m = fmaxf(m, __shfl_xor(m, 8));
      m *= scale;
      float s = 0.f;
#pragma unroll
      for (int ct = 0; ct < 16; ++ct) {
        float p = __expf(sa[ct][j] * scale - m);
        sa[ct][j] = p;
        s += p;
      }
      s += __shfl_xor(s, 1);
      s += __shfl_xor(s, 2);
      s += __shfl_xor(s, 4);
      s += __shfl_xor(s, 8);
      float inv = 1.f / s;
#pragma unroll
      for (int ct = 0; ct < 16; ++ct) sa[ct][j] *= inv;
    }

    // O = P V in four key-quarters through the per-wave swizzled LDS P tile.
    // In-wave DS ordering makes write->read->overwrite safe without barriers.
    f32x4 oacc[4] = {};
#pragma unroll
    for (int kh = 0; kh < 4; ++kh) {
#pragma unroll
      for (int c = 0; c < 4; ++c)
#pragma unroll
        for (int j = 0; j < 4; ++j) {
          int rq = g4 * 4 + j;
          PW[rq * 64 + (((2 * c + (ro >> 3)) ^ (rq & 7)) * 8) + (ro & 7)] =
              f2bf(sa[kh * 4 + c][j]);
        }
      __builtin_amdgcn_s_setprio(1);
#pragma unroll
      for (int ks = 0; ks < 2; ++ks) {
        bf16x8 pf = ldf(PW + ro * 64 + (((ks * 4 + g4) ^ (ro & 7)) * 8));
        const int kkg = kh * 2 + ks;
#pragma unroll
        for (int cd = 0; cd < 4; ++cd) {
          bf16x8 vf = ldf(Vt + (16 * cd + ro) * 256 + (((kkg * 4 + g4) ^ (ro & 7)) * 8));
          oacc[cd] = __builtin_amdgcn_mfma_f32_16x16x32_bf16(pf, vf, oacc[cd], 0, 0, 0);
        }
      }
      __builtin_amdgcn_s_setprio(0);
    }

    // write out this 16-row tile
#pragma unroll
    for (int cd = 0; cd < 4; ++cd)
#pragma unroll
      for (int j = 0; j < 4; ++j) {
        int t = 32 * wv + 16 * rt + g4 * 4 + j;
        int d = 16 * cd + ro;
        o[((size_t)(b * LL + lrow(t))) * 512 + h * 64 + d] = f2bf(oacc[cd][j]);
      }
  }
}

// ---------------- launch ----------------
extern "C" void kernel_launch(void* const* d_in, const int* in_sizes, int n_in,
                              void* d_out, int out_size, void* d_ws, size_t ws_size,
                              hipStream_t stream) {
  const float* q = (const float*)d_in[0];
  const float* kv = (const float*)d_in[1];
  const float* Wq = (const float*)d_in[2];
  const float* Wkv = (const float*)d_in[3];
  const float* Wfc = (const float*)d_in[4];
  float* out = (float*)d_out;
  char* ws = (char*)d_ws;

  // workspace layout (bytes)
  u16* q_bf  = (u16*)(ws + 0);            // 67108864  (also reused as o_buf)
  u16* kv_bf = (u16*)(ws + 67108864);     // 67108864
  u16* qp    = (u16*)(ws + 134217728);    // 67108864
  u16* kvp   = (u16*)(ws + 201326592);    // 134217728
  u16* Wq_t  = (u16*)(ws + 335544320);    // 524288
  u16* Wkv_t = (u16*)(ws + 336068608);    // 1048576
  u16* Wfc_t = (u16*)(ws + 337117184);    // 524288
  u16* o_buf = q_bf;                      // q_bf dead after GEMM1

  const int n4 = MM * CC / 4;  // 8388608
  cvt2_kernel<<<4096, 256, 0, stream>>>(q, kv, q_bf, kv_bf, n4);
  tcvt3_kernel<<<4096, 256, 0, stream>>>(Wq, Wkv, Wfc, Wq_t, Wkv_t, Wfc_t);

  gemm256<false><<<(MM / 256) * (CC / 256), 512, 0, stream>>>(q_bf, Wq_t, qp, MM, CC, CC);
  gemm256<false><<<(MM / 256) * (2 * CC / 256), 512, 0, stream>>>(kv_bf, Wkv_t, kvp, MM, 2 * CC, CC);

  attn_kernel<<<BB * 64 * 8, 512, 0, stream>>>(qp, kvp, o_buf);

  gemm256<true><<<(MM / 256) * (CC / 256), 512, 0, stream>>>(o_buf, Wfc_t, out, MM, CC, CC);
}